// Round 1
// baseline (137.294 us; speedup 1.0000x reference)
//
#include <hip/hip_runtime.h>

#define N_NODES 50000
#define N_EDGES 800000
#define D 128
#define LDA 136   // padded LDS row stride in shorts (+4 banks/row -> 2-way alias, free)

#define SEARCH_BLOCKS 196   // ceil(50001/256)
#define GEMM_BLOCKS   391   // ceil(50000/128)

typedef __attribute__((ext_vector_type(8))) short bf16x8;
typedef __attribute__((ext_vector_type(4))) float f32x4;

__device__ __forceinline__ unsigned short f2bf(float f) {
    union { float f; unsigned u; } v; v.f = f;
    return (unsigned short)((v.u + 0x7fffu + ((v.u >> 16) & 1u)) >> 16);
}
__device__ __forceinline__ float bflo(unsigned u) {
    union { unsigned u; float f; } c; c.u = u << 16; return c.f;
}
__device__ __forceinline__ float bfhi(unsigned u) {
    union { unsigned u; float f; } c; c.u = u & 0xffff0000u; return c.f;
}

// ------- KH: fused row_ptr searches + dst compaction + (h = bf16(X)@bf16(W) MFMA) ----
// Blocks [0, SEARCH_BLOCKS): lower_bound(src, n) -> row_ptr, plus dst column compaction.
// Blocks [SEARCH_BLOCKS, ...): 128-row GEMM tile. A-fragments come straight from
// global memory (16 rows x 128B contiguous per wave-load) -> no A LDS round-trip,
// LDS = 35.8 KB -> 4 blocks/CU.
__global__ __launch_bounds__(256) void kh_fused(const float* __restrict__ X,
                                                const int* __restrict__ edges,
                                                const float* __restrict__ W,
                                                const float* __restrict__ ka,
                                                unsigned short* __restrict__ h,
                                                float* __restrict__ a_src,
                                                float* __restrict__ a_dst,
                                                int* __restrict__ row_ptr,
                                                int* __restrict__ dst32) {
    __shared__ unsigned short Bs[128 * LDA];   // [n][k], 34.8 KB
    __shared__ float kas[2 * D];               // 1 KB
    int b = blockIdx.x, tid = threadIdx.x;

    if (b < SEARCH_BLOCKS) {                   // row_ptr[n] = lower_bound(src, n)
        int n = b * 256 + tid;
        if (n <= N_NODES) {
            int lo = 0, hi = N_EDGES;
            while (lo < hi) {
                int mid = (lo + hi) >> 1;
                if (edges[2 * mid] < n) lo = mid + 1; else hi = mid;
            }
            row_ptr[n] = lo;
        }
        // compact dst column -> coalesced 4B reads in k3
        for (int e = b * 256 + tid; e < N_EDGES; e += SEARCH_BLOCKS * 256)
            dst32[e] = edges[2 * e + 1];
        return;
    }

    int row0 = (b - SEARCH_BLOCKS) * 128;
    kas[tid] = ka[tid];
    // Bs <- bf16(W^T): thread reads W[k][n4..n4+3] coalesced, scatters 4 u16.
    for (int i = tid; i < 128 * 32; i += 256) {
        int k = i >> 5, n4 = (i & 31) * 4;
        float4 w = *(const float4*)(W + k * D + n4);
        Bs[(n4 + 0) * LDA + k] = f2bf(w.x);
        Bs[(n4 + 1) * LDA + k] = f2bf(w.y);
        Bs[(n4 + 2) * LDA + k] = f2bf(w.z);
        Bs[(n4 + 3) * LDA + k] = f2bf(w.w);
    }
    __syncthreads();

    int wave = tid >> 6, lane = tid & 63;
    int m16 = lane & 15, quad = lane >> 4;
    int wr0 = wave * 32;                       // 2 row-tiles per wave
    // direct-A: lane owns row (wr0+m16) / (wr0+16+m16), k = k0 + quad*8 .. +7
    int gr0 = min(row0 + wr0 + m16, N_NODES - 1);        // clamp: garbage rows guarded at store
    int gr1 = min(row0 + wr0 + 16 + m16, N_NODES - 1);
    const float* x0 = X + (size_t)gr0 * D + quad * 8;
    const float* x1 = X + (size_t)gr1 * D + quad * 8;

    f32x4 acc[2][8];
#pragma unroll
    for (int i = 0; i < 2; ++i)
#pragma unroll
        for (int j = 0; j < 8; ++j) acc[i][j] = (f32x4){0.f, 0.f, 0.f, 0.f};

#pragma unroll
    for (int k0 = 0; k0 < D; k0 += 32) {
        f32x4 f00 = __builtin_nontemporal_load((const f32x4*)(x0 + k0));
        f32x4 f01 = __builtin_nontemporal_load((const f32x4*)(x0 + k0 + 4));
        f32x4 f10 = __builtin_nontemporal_load((const f32x4*)(x1 + k0));
        f32x4 f11 = __builtin_nontemporal_load((const f32x4*)(x1 + k0 + 4));
        union { unsigned short us[8]; bf16x8 v; } ua0, ua1;
#pragma unroll
        for (int j = 0; j < 4; ++j) { ua0.us[j] = f2bf(f00[j]); ua0.us[4 + j] = f2bf(f01[j]); }
#pragma unroll
        for (int j = 0; j < 4; ++j) { ua1.us[j] = f2bf(f10[j]); ua1.us[4 + j] = f2bf(f11[j]); }
#pragma unroll
        for (int j = 0; j < 8; ++j) {
            bf16x8 bf = *(const bf16x8*)&Bs[(j * 16 + m16) * LDA + k0 + quad * 8];
            acc[0][j] = __builtin_amdgcn_mfma_f32_16x16x32_bf16(ua0.v, bf, acc[0][j], 0, 0, 0);
            acc[1][j] = __builtin_amdgcn_mfma_f32_16x16x32_bf16(ua1.v, bf, acc[1][j], 0, 0, 0);
        }
    }

    // h store: C/D layout col=lane&15, row=quad*4+reg (m89-verified)
#pragma unroll
    for (int i = 0; i < 2; ++i)
#pragma unroll
        for (int j = 0; j < 8; ++j)
#pragma unroll
            for (int r = 0; r < 4; ++r) {
                int row = row0 + wr0 + i * 16 + quad * 4 + r;
                if (row < N_NODES)
                    h[(size_t)row * D + j * 16 + m16] = f2bf(acc[i][j][r]);
            }

    // a_src/a_dst from fp32 accumulators: a_src[row] = sum_col h[row][col]*ka[col]
#pragma unroll
    for (int i = 0; i < 2; ++i)
#pragma unroll
        for (int r = 0; r < 4; ++r) {
            float ps = 0.f, pd = 0.f;
#pragma unroll
            for (int j = 0; j < 8; ++j) {
                float val = acc[i][j][r];
                ps += val * kas[j * 16 + m16];
                pd += val * kas[D + j * 16 + m16];
            }
            for (int off = 8; off > 0; off >>= 1) {
                ps += __shfl_down(ps, off, 16);
                pd += __shfl_down(pd, off, 16);
            }
            int row = row0 + wr0 + i * 16 + quad * 4 + r;
            if (m16 == 0 && row < N_NODES) { a_src[row] = ps; a_dst[row] = pd; }
        }
}

// ---------------- K3: quarter-wave (16 lanes) per node, 8 rows in flight/lane ------
// 16 lanes cover a 128-col row (uint4 = 8 bf16 each). No cross-quad shuffles,
// no final reduction: every lane accumulates full dn and its own 8 columns.
__global__ __launch_bounds__(256) void k3(const int* __restrict__ dst32,
                                          const int* __restrict__ row_ptr,
                                          const unsigned short* __restrict__ h,
                                          const float* __restrict__ a_src,
                                          const float* __restrict__ a_dst,
                                          float* __restrict__ out) {
    int node = blockIdx.x * 16 + (threadIdx.x >> 4);   // grid = 3125 -> exactly 50000
    int l16 = threadIdx.x & 15;

    int start = row_ptr[node], end = row_ptr[node + 1];
    float asn = a_src[node];
    const unsigned short* hl = h + (l16 << 3);

    float accv[8] = {0.f, 0.f, 0.f, 0.f, 0.f, 0.f, 0.f, 0.f};
    float dn = 0.f;

    for (int base = start; base < end; base += 16) {
        int cnt = min(16, end - base);
        int dd = 0; float s = 0.f;
        if (l16 < cnt) {                        // all 16 lanes do score work
            dd = dst32[base + l16];
            float lg = asn + a_dst[dd];
            lg = (lg >= 0.f) ? lg : 0.2f * lg;  // leaky_relu 0.2
            lg = fminf(fmaxf(lg, -2.f), 2.f);   // clip
            s = __expf(lg);
        }
        for (int t0 = 0; t0 < cnt; t0 += 8) {   // 8 gather loads in flight per lane
            float sj[8]; int dj[8]; uint4 p[8];
#pragma unroll
            for (int t = 0; t < 8; ++t) {
                sj[t] = __shfl(s, t0 + t, 16);  // dead slots -> s=0
                dj[t] = __shfl(dd, t0 + t, 16); // dead slots -> row 0 (L1-hot)
            }
#pragma unroll
            for (int t = 0; t < 8; ++t)
                p[t] = *(const uint4*)(hl + ((size_t)dj[t] << 7));
#pragma unroll
            for (int t = 0; t < 8; ++t) {
                float sv = sj[t];
                accv[0] += sv * bflo(p[t].x); accv[1] += sv * bfhi(p[t].x);
                accv[2] += sv * bflo(p[t].y); accv[3] += sv * bfhi(p[t].y);
                accv[4] += sv * bflo(p[t].z); accv[5] += sv * bfhi(p[t].z);
                accv[6] += sv * bflo(p[t].w); accv[7] += sv * bfhi(p[t].w);
                dn += sv;
            }
        }
    }

    float inv = (end > start) ? 1.f / dn : 0.f;
    f32x4 o0 = {accv[0] * inv, accv[1] * inv, accv[2] * inv, accv[3] * inv};
    f32x4 o1 = {accv[4] * inv, accv[5] * inv, accv[6] * inv, accv[7] * inv};
    float* op = out + (size_t)node * D + l16 * 8;
    __builtin_nontemporal_store(o0, (f32x4*)op);        // out never re-read: keep L2 for h
    __builtin_nontemporal_store(o1, (f32x4*)(op + 4));
}

extern "C" void kernel_launch(void* const* d_in, const int* in_sizes, int n_in,
                              void* d_out, int out_size, void* d_ws, size_t ws_size,
                              hipStream_t stream) {
    const float* X     = (const float*)d_in[0];   // 50000 x 128
    const int*   edges = (const int*)d_in[1];     // 800000 x 2 (src,dst), src sorted
    const float* W     = (const float*)d_in[2];   // 128 x 128
    const float* ka    = (const float*)d_in[3];   // 256 x 1

    char* ws = (char*)d_ws;
    unsigned short* h  = (unsigned short*)ws;                       // 12.8 MB bf16
    float* a_src   = (float*)(ws + (size_t)N_NODES * D * 2);        // 200 KB
    float* a_dst   = a_src + N_NODES;                               // 200 KB
    int*   row_ptr = (int*)(a_dst + N_NODES);                       // 50001 ints
    int*   dst32   = row_ptr + ((N_NODES + 16) & ~15);              // 3.2 MB
    float* out = (float*)d_out;

    kh_fused<<<SEARCH_BLOCKS + GEMM_BLOCKS, 256, 0, stream>>>(
        X, edges, W, ka, h, a_src, a_dst, row_ptr, dst32);
    k3<<<(N_NODES + 15) / 16, 256, 0, stream>>>(dst32, row_ptr, h, a_src, a_dst, out);
}

// Round 2
// 129.638 us; speedup vs baseline: 1.0591x; 1.0591x over previous
//
#include <hip/hip_runtime.h>

#define N_NODES 50000
#define N_EDGES 800000
#define D 128
#define LDA 136   // padded LDS row stride in shorts (+4 banks/row -> 2-way alias, free)

#define SEARCH_BLOCKS 196   // ceil(50001/256)
#define GEMM_BLOCKS   391   // ceil(50000/128)

typedef __attribute__((ext_vector_type(8))) short bf16x8;
typedef __attribute__((ext_vector_type(4))) float f32x4;

__device__ __forceinline__ unsigned short f2bf(float f) {
    union { float f; unsigned u; } v; v.f = f;
    return (unsigned short)((v.u + 0x7fffu + ((v.u >> 16) & 1u)) >> 16);
}
__device__ __forceinline__ float bflo(unsigned u) {
    union { unsigned u; float f; } c; c.u = u << 16; return c.f;
}
__device__ __forceinline__ float bfhi(unsigned u) {
    union { unsigned u; float f; } c; c.u = u & 0xffff0000u; return c.f;
}

// ------- KH: fused row_ptr searches + (h = bf16(X)@bf16(W) MFMA, a_src/a_dst) ----
// Round-0 verified structure. Only change: A-staging uses explicit float4 loads.
__global__ __launch_bounds__(256) void kh_fused(const float* __restrict__ X,
                                                const int* __restrict__ edges,
                                                const float* __restrict__ W,
                                                const float* __restrict__ ka,
                                                unsigned short* __restrict__ h,
                                                float* __restrict__ a_src,
                                                float* __restrict__ a_dst,
                                                int* __restrict__ row_ptr) {
    __shared__ unsigned short As[128 * LDA];   // [m][k], 34.8 KB
    __shared__ unsigned short Bs[128 * LDA];   // [n][k], 34.8 KB
    __shared__ float kas[2 * D];               // 1 KB
    int b = blockIdx.x, tid = threadIdx.x;

    if (b < SEARCH_BLOCKS) {                   // row_ptr[n] = lower_bound(src, n)
        int n = b * 256 + tid;
        if (n > N_NODES) return;
        int lo = 0, hi = N_EDGES;
        while (lo < hi) {
            int mid = (lo + hi) >> 1;
            if (edges[2 * mid] < n) lo = mid + 1; else hi = mid;
        }
        row_ptr[n] = lo;
        return;
    }

    int row0 = (b - SEARCH_BLOCKS) * 128;
    kas[tid] = ka[tid];
    // Bs <- bf16(W^T): thread reads W[k][n4..n4+3] coalesced, scatters 4 u16.
    for (int i = tid; i < 128 * 32; i += 256) {
        int k = i >> 5, n4 = (i & 31) * 4;
        float4 w = *(const float4*)(W + k * D + n4);
        Bs[(n4 + 0) * LDA + k] = f2bf(w.x);
        Bs[(n4 + 1) * LDA + k] = f2bf(w.y);
        Bs[(n4 + 2) * LDA + k] = f2bf(w.z);
        Bs[(n4 + 3) * LDA + k] = f2bf(w.w);
    }
    // As <- bf16(X tile), float4 loads (16B/lane, G13)
    for (int i = tid; i < 2048; i += 256) {
        int r = i >> 4, c = i & 15;
        int gr = row0 + r;
        union { unsigned short us[8]; uint4 q; } pk;
        if (gr < N_NODES) {
            const float* xp = X + (size_t)gr * D + c * 8;
            float4 u = *(const float4*)xp;
            float4 v = *(const float4*)(xp + 4);
            pk.us[0] = f2bf(u.x); pk.us[1] = f2bf(u.y);
            pk.us[2] = f2bf(u.z); pk.us[3] = f2bf(u.w);
            pk.us[4] = f2bf(v.x); pk.us[5] = f2bf(v.y);
            pk.us[6] = f2bf(v.z); pk.us[7] = f2bf(v.w);
        } else pk.q = make_uint4(0u, 0u, 0u, 0u);
        *(uint4*)&As[r * LDA + c * 8] = pk.q;
    }
    __syncthreads();

    int wave = tid >> 6, lane = tid & 63;
    int m16 = lane & 15, quad = lane >> 4;
    int wr0 = wave * 32;                       // 2 row-tiles per wave
    f32x4 acc[2][8];
#pragma unroll
    for (int i = 0; i < 2; ++i)
#pragma unroll
        for (int j = 0; j < 8; ++j) acc[i][j] = (f32x4){0.f, 0.f, 0.f, 0.f};

    for (int k0 = 0; k0 < D; k0 += 32) {
        bf16x8 a0 = *(const bf16x8*)&As[(wr0 + m16) * LDA + k0 + quad * 8];
        bf16x8 a1 = *(const bf16x8*)&As[(wr0 + 16 + m16) * LDA + k0 + quad * 8];
#pragma unroll
        for (int j = 0; j < 8; ++j) {
            bf16x8 bf = *(const bf16x8*)&Bs[(j * 16 + m16) * LDA + k0 + quad * 8];
            acc[0][j] = __builtin_amdgcn_mfma_f32_16x16x32_bf16(a0, bf, acc[0][j], 0, 0, 0);
            acc[1][j] = __builtin_amdgcn_mfma_f32_16x16x32_bf16(a1, bf, acc[1][j], 0, 0, 0);
        }
    }

    // h store: C/D layout col=lane&15, row=quad*4+reg (m89-verified)
#pragma unroll
    for (int i = 0; i < 2; ++i)
#pragma unroll
        for (int j = 0; j < 8; ++j)
#pragma unroll
            for (int r = 0; r < 4; ++r) {
                int row = row0 + wr0 + i * 16 + quad * 4 + r;
                if (row < N_NODES)
                    h[(size_t)row * D + j * 16 + m16] = f2bf(acc[i][j][r]);
            }

    // a_src/a_dst from fp32 accumulators: a_src[row] = sum_col h[row][col]*ka[col]
#pragma unroll
    for (int i = 0; i < 2; ++i)
#pragma unroll
        for (int r = 0; r < 4; ++r) {
            float ps = 0.f, pd = 0.f;
#pragma unroll
            for (int j = 0; j < 8; ++j) {
                float val = acc[i][j][r];
                ps += val * kas[j * 16 + m16];
                pd += val * kas[D + j * 16 + m16];
            }
            for (int off = 8; off > 0; off >>= 1) {
                ps += __shfl_down(ps, off, 16);
                pd += __shfl_down(pd, off, 16);
            }
            int row = row0 + wr0 + i * 16 + quad * 4 + r;
            if (m16 == 0 && row < N_NODES) { a_src[row] = ps; a_dst[row] = pd; }
        }
}

// ---------------- K2: flat per-edge score precompute -------------------------
// Coalesced int2 edge read; a_src/a_dst are 200 KB each -> L2-resident gathers.
// Hoists the leaky/clip/expf chain out of k3's latency-critical wave loop.
__global__ __launch_bounds__(256) void k2_scores(const int* __restrict__ edges,
                                                 const float* __restrict__ a_src,
                                                 const float* __restrict__ a_dst,
                                                 float* __restrict__ scores) {
    int e = blockIdx.x * 256 + threadIdx.x;
    if (e >= N_EDGES) return;
    int2 sd = ((const int2*)edges)[e];
    float lg = a_src[sd.x] + a_dst[sd.y];
    lg = (lg >= 0.f) ? lg : 0.2f * lg;          // leaky_relu 0.2
    lg = fminf(fmaxf(lg, -2.f), 2.f);           // clip
    scores[e] = __expf(lg);
}

// ---------------- K3: wave-per-node gather, 4 loads in flight (round-0) -----
// Score phase is now two coalesced loads (d, s) -- no VALU chain, no a_dst gather.
__global__ __launch_bounds__(256) void k3(const int* __restrict__ edges,
                                          const int* __restrict__ row_ptr,
                                          const float* __restrict__ scores,
                                          const unsigned short* __restrict__ h,
                                          float* __restrict__ out) {
    int node = blockIdx.x * 4 + (threadIdx.x >> 6);
    if (node >= N_NODES) return;
    int lane = threadIdx.x & 63;
    int q = lane >> 4;          // quarter-wave 0..3
    int l16 = lane & 15;        // 16 lanes x 8 cols cover a 128-col row

    int start = row_ptr[node], end = row_ptr[node + 1];

    float4 accA = make_float4(0.f, 0.f, 0.f, 0.f);
    float4 accB = make_float4(0.f, 0.f, 0.f, 0.f);
    float dn = 0.f;

    for (int base = start; base < end; base += 64) {
        int cnt = min(64, end - base);
        int d = 0; float s = 0.f;
        if (lane < cnt) {
            d = edges[2 * (base + lane) + 1];
            s = scores[base + lane];
        }
        for (int j = 0; j < cnt; j += 16) {         // 16 edges/iter, 4 loads/lane in flight
            float sj[4]; int dj[4];
#pragma unroll
            for (int t = 0; t < 4; ++t) {
                sj[t] = __shfl(s, j + q + 4 * t, 64);   // 0 for dead slots
                dj[t] = __shfl(d, j + q + 4 * t, 64);   // 0 for dead slots -> hot row 0
            }
            uint4 p[4];
#pragma unroll
            for (int t = 0; t < 4; ++t)
                p[t] = *(const uint4*)(h + ((size_t)dj[t] << 7) + (l16 << 3));
#pragma unroll
            for (int t = 0; t < 4; ++t) {
                float sv = sj[t];
                accA.x += sv * bflo(p[t].x); accA.y += sv * bfhi(p[t].x);
                accA.z += sv * bflo(p[t].y); accA.w += sv * bfhi(p[t].y);
                accB.x += sv * bflo(p[t].z); accB.y += sv * bfhi(p[t].z);
                accB.z += sv * bflo(p[t].w); accB.w += sv * bfhi(p[t].w);
                dn += sv;
            }
        }
    }

    float vals[9] = {accA.x, accA.y, accA.z, accA.w,
                     accB.x, accB.y, accB.z, accB.w, dn};
#pragma unroll
    for (int m = 32; m >= 16; m >>= 1)
#pragma unroll
        for (int i = 0; i < 9; ++i) vals[i] += __shfl_xor(vals[i], m, 64);

    if (q == 0) {
        float inv = (end > start) ? 1.f / vals[8] : 0.f;
        f32x4 o0 = {vals[0] * inv, vals[1] * inv, vals[2] * inv, vals[3] * inv};
        f32x4 o1 = {vals[4] * inv, vals[5] * inv, vals[6] * inv, vals[7] * inv};
        float* op = out + (size_t)node * D + l16 * 8;
        __builtin_nontemporal_store(o0, (f32x4*)op);       // out never re-read: keep L2 for h
        __builtin_nontemporal_store(o1, (f32x4*)(op + 4));
    }
}

extern "C" void kernel_launch(void* const* d_in, const int* in_sizes, int n_in,
                              void* d_out, int out_size, void* d_ws, size_t ws_size,
                              hipStream_t stream) {
    const float* X     = (const float*)d_in[0];   // 50000 x 128
    const int*   edges = (const int*)d_in[1];     // 800000 x 2 (src,dst), src sorted
    const float* W     = (const float*)d_in[2];   // 128 x 128
    const float* ka    = (const float*)d_in[3];   // 256 x 1

    char* ws = (char*)d_ws;
    unsigned short* h  = (unsigned short*)ws;                       // 12.8 MB bf16
    float* a_src   = (float*)(ws + (size_t)N_NODES * D * 2);        // 200 KB
    float* a_dst   = a_src + N_NODES;                               // 200 KB
    int*   row_ptr = (int*)(a_dst + N_NODES);                       // 50001 ints
    float* scores  = (float*)(row_ptr + ((N_NODES + 16) & ~15));    // 3.2 MB
    float* out = (float*)d_out;

    kh_fused<<<SEARCH_BLOCKS + GEMM_BLOCKS, 256, 0, stream>>>(
        X, edges, W, ka, h, a_src, a_dst, row_ptr);
    k2_scores<<<(N_EDGES + 255) / 256, 256, 0, stream>>>(edges, a_src, a_dst, scores);
    k3<<<(N_NODES + 3) / 4, 256, 0, stream>>>(edges, row_ptr, scores, h, out);
}